// Round 18
// baseline (768.982 us; speedup 1.0000x reference)
//
#include <hip/hip_runtime.h>
#include <hip/hip_bf16.h>
#include <math.h>

#define BB 32
#define LL 1024
#define DD 256
#define HH 256
#define NG 7
#define HW (HH*HH)       /* 65536 */
#define WhS (2*HH*HH)    /* Wh per-gate stride */

typedef short bf16x8 __attribute__((ext_vector_type(8)));
typedef float f32x4  __attribute__((ext_vector_type(4)));
typedef unsigned short u16;
typedef unsigned int u32;

__device__ __forceinline__ float sigm(float x){ return 1.0f/(1.0f + expf(-x)); }
__device__ __forceinline__ float fsig(float x){ return __fdividef(1.0f, 1.0f + __expf(-x)); }
__device__ __forceinline__ float ftanh(float x){ return 1.0f - __fdividef(2.0f, 1.0f + __expf(2.0f*x)); }
__device__ __forceinline__ u16 f2b(float f){
  u32 u = __float_as_uint(f);
  return (u16)((u + 0x7fffu + ((u>>16)&1u)) >> 16);   // RNE
}
__device__ __forceinline__ float b2f(u16 b){ return __uint_as_float(((u32)b)<<16); }
__device__ __forceinline__ float4 ld4(const float* p){ return *reinterpret_cast<const float4*>(p); }
__device__ __forceinline__ u32 packf2(float lo, float hi){
  float2 s; s.x = lo; s.y = hi;
  __hip_bfloat162 r = __float22bfloat162_rn(s);
  return *reinterpret_cast<u32*>(&r);
}
// sum of two bf16 pairs (packed dwords), RNE back to packed bf16
__device__ __forceinline__ u32 bfadd2(u32 a, u32 b){
  float lo = __uint_as_float(a << 16)        + __uint_as_float(b << 16);
  float hi = __uint_as_float(a & 0xffff0000u) + __uint_as_float(b & 0xffff0000u);
  return packf2(lo, hi);
}

__device__ __forceinline__ void gload16(const void* g, void* l){
  __builtin_amdgcn_global_load_lds(
    (const __attribute__((address_space(1))) unsigned int*)g,
    (__attribute__((address_space(3))) unsigned int*)l, 16, 0, 0);
}
__device__ __forceinline__ f32x4 mfma16(bf16x8 a, bf16x8 b, f32x4 c){
  return __builtin_amdgcn_mfma_f32_16x16x32_bf16(a, b, c, 0, 0, 0);
}

// ---------------- init: h,c + layer-0 mean partials ----------------
__global__ __launch_bounds__(256) void k_init(const float* __restrict__ ih, const float* __restrict__ ic,
    const int* __restrict__ mask, u16* __restrict__ h, float* __restrict__ c,
    float* __restrict__ pmh, float* __restrict__ pmc){
  int b = blockIdx.x, ch = blockIdx.y, k = threadIdx.x;
  size_t base = ((size_t)b*LL + ch*64)*HH + k;
  float sh = 0.f, sc = 0.f;
  for (int l = 0; l < 64; ++l){
    size_t idx = base + (size_t)l*HH;
    float fm = (float)mask[b*LL + ch*64 + l];
    float hv = (ih[idx]*0.1f - 0.05f)*fm;
    float cv = (ic[idx]*0.1f - 0.05f)*fm;
    h[idx] = f2b(hv);
    c[idx] = cv;
    sh += hv; sc += cv;
  }
  pmh[(size_t)(b*16+ch)*HH + k] = sh;
  pmc[(size_t)(b*16+ch)*HH + k] = sc;
}

// ---------------- emb precompute (once per call): embp = bf16(win*mask) ----------------
__global__ __launch_bounds__(256) void k_embpack(const float* __restrict__ win,
    const int* __restrict__ mask, u16* __restrict__ embp){
  int idx = blockIdx.x*256 + threadIdx.x;     // 0..1048575 (8 elems each)
  int m = idx >> 5, c8 = (idx & 31) << 3;
  float fm = (float)mask[m];
  float4 w0 = ld4(win + (size_t)m*DD + c8);
  float4 w1 = ld4(win + (size_t)m*DD + c8 + 4);
  uint4 pv;
  pv.x = packf2(w0.x*fm, w0.y*fm); pv.y = packf2(w0.z*fm, w0.w*fm);
  pv.z = packf2(w1.x*fm, w1.y*fm); pv.w = packf2(w1.z*fm, w1.w*fm);
  *(uint4*)(embp + (size_t)m*HH + c8) = pv;
}

// ---------------- fused mean + small GEMMs, grid (BB, 8) ----------------
__global__ __launch_bounds__(256) void k_ms(const float* __restrict__ pmh, const float* __restrict__ pmc,
    const float* __restrict__ dh_in,
    const float* __restrict__ gWx, const float* __restrict__ gWh, const float* __restrict__ gb,
    const float* __restrict__ Wd, const float* __restrict__ bias,
    float* __restrict__ g_d, float* __restrict__ g_o, float* __restrict__ gx2f, float* __restrict__ wd,
    float* __restrict__ combc_out, int l0flag){
  __shared__ float dsh[HH], csh[HH];
  int b = blockIdx.x, g = blockIdx.y, k = threadIdx.x;
  float sh = 0.f;
  for (int ch = 0; ch < 16; ++ch) sh += pmh[(size_t)(b*16+ch)*HH + k];
  float comb = sh*(1.0f/LL);
  csh[k] = comb;
  dsh[k] = l0flag ? comb : dh_in[b*HH+k];
  __syncthreads();
  if (g < NG){
    float aw = bias[g*HH+k];
    const float* W = Wd + (size_t)g*HW + k;
    for (int j = 0; j < HH; ++j) aw += dsh[j]*W[(size_t)j*HH];
    wd[(size_t)(g*BB + b)*HH + k] = aw;
  } else {
    float ad = gb[0*HH+k], ao = gb[1*HH+k], ax = gb[2*HH+k];
    for (int j = 0; j < HH; ++j){
      float dv = dsh[j], cv = csh[j];
      ad += dv*gWx[j*HH+k]      + cv*gWh[j*HH+k];
      ao += dv*gWx[HW + j*HH+k] + cv*gWh[HW + j*HH+k];
      ax += dv*gWx[2*HW + j*HH+k];
    }
    g_d[b*HH+k] = sigm(ad);
    g_o[b*HH+k] = sigm(ao);
    gx2f[b*HH+k] = ax;
    if (l0flag){
      float sc = 0.f;
      for (int ch = 0; ch < 16; ++ch) sc += pmc[(size_t)(b*16+ch)*HH + k];
      combc_out[b*HH+k] = sc*(1.0f/LL);
    }
  }
}

// ---------------- weight pack: frag-contiguous (B read direct from L2) ----------------
__global__ __launch_bounds__(256) void k_wpack(const float* __restrict__ Wx, const float* __restrict__ Wh,
    const float* __restrict__ Wi, u16* __restrict__ Bp){
  int idx = blockIdx.x*256 + threadIdx.x;      // 0..1835007
  int img = idx / 14336, e = idx % 14336;
  int nt = img >> 5, ks = img & 31;
  int g = e >> 11, r = e & 2047;
  int n = r >> 5, kblk = (r>>3)&3, j = r&7;
  int K = ks*32 + kblk*8 + j;
  int N = nt*64 + n;
  int slice = K >> 8, kr = K & 255;
  float v;
  if (slice == 0)      v = Wx[(size_t)g*HW  + (size_t)kr*HH + N];
  else if (slice == 1) v = Wh[(size_t)g*WhS + (size_t)kr*HH + N];
  else if (slice == 2) v = Wh[(size_t)g*WhS + (size_t)(256+kr)*HH + N];
  else                 v = Wi[(size_t)g*HW  + (size_t)kr*HH + N];
  Bp[idx] = f2b(v);
}

__global__ __launch_bounds__(256) void k_gw2pack(const float* __restrict__ gWh, u16* __restrict__ Gp){
  int idx = blockIdx.x*256 + threadIdx.x;      // 0..65535
  int img = idx >> 11, r = idx & 2047;         // img = nt*8+ks
  int nt = img >> 3, ks = img & 7;
  int n = r >> 5, kblk = (r>>3)&3, j = r&7;
  int K = ks*32 + kblk*8 + j, N = nt*64 + n;
  Gp[idx] = f2b(gWh[2*HW + (size_t)K*HH + N]);
}

__global__ __launch_bounds__(256) void k_dummy2(const float* __restrict__ pnumP, const float* __restrict__ pdenP,
    const float* __restrict__ g_d, const float* __restrict__ g_o, const float* __restrict__ dc,
    float* __restrict__ dh_n, float* __restrict__ dc_n){
  int b = blockIdx.x, k = threadIdx.x;
  float num = 0.f, den = 0.f;
  for (int mt = 0; mt < 16; ++mt){
    num += pnumP[(size_t)(b*16+mt)*HH + k];
    den += pdenP[(size_t)(b*16+mt)*HH + k];
  }
  float ed = expf(g_d[b*HH+k]);
  float v = (num + ed*dc[b*HH+k])/(den + ed);
  dc_n[b*HH+k] = v;
  dh_n[b*HH+k] = g_o[b*HH+k]*tanhf(v);
}

// ================= TWO-PASS main GEMM (gate split in time) =================
// PASS 0: gates 0-3 -> raw pre-activations stored packed bf16x4 (pre4).
// PASS 1: gates 4-6 + g_f + full epilogue (reads pre4).
// acc = 64 regs/wave -> __launch_bounds__(256,3): 3 waves/SIMD (+50% TLP).
template<int PASS>
__global__ __launch_bounds__(256, 3) void k_mainP(const u16* __restrict__ h,
    const float* __restrict__ c, const u16* __restrict__ embp,
    const int* __restrict__ mask,
    const u16* __restrict__ Bp, const u16* __restrict__ Gp,
    const float* __restrict__ wd, const float* __restrict__ dc,
    const float* __restrict__ gx2f, ushort4* __restrict__ pre4,
    u16* __restrict__ hout, float* __restrict__ cout, float* __restrict__ hf32,
    float* __restrict__ pnumP, float* __restrict__ pdenP,
    float* __restrict__ pmh, float* __restrict__ pmc, int wf32, int wc){
  __shared__ __align__(16) unsigned char lsA[3][4][4096];   // 48 KB

  int tid = threadIdx.x, lane = tid & 63, wid = tid >> 6;
  int flat = blockIdx.x;
  int xcd = flat & 7, q = flat >> 3;
  int nt  = xcd >> 1;
  int mt  = (xcd & 1)*256 + q;
  int m0 = mt << 6, b = m0 >> 10;
  int li = lane & 15, kg = lane >> 4;

  int kbA = (lane&3) ^ ((lane>>3)&3);
  int mA = m0 + wid*16 + (lane>>2), lpA = mA & (LL-1);
  int off0 = li*64 + ((kg ^ ((li>>1)&3))<<4);

  const unsigned char* bbase = (const unsigned char*)Bp
      + (size_t)nt*32*28672 + (size_t)(wid*16+li)*64 + (size_t)kg*16;
  const unsigned char* gbase = (const unsigned char*)Gp
      + (size_t)nt*8*4096  + (size_t)(wid*16+li)*64 + (size_t)kg*16;

  f32x4 acc[4][4];
  #pragma unroll
  for (int u=0; u<4; ++u)
    #pragma unroll
    for (int mf=0; mf<4; ++mf) acc[u][mf] = (f32x4)0.f;

  auto stage = [&](int Gs, int dst){
    int base = 4*Gs, s1 = base >> 3;
    if (s1 == 0 || s1 == 3){
      const u16* src = (s1 == 0) ? h : embp;
      #pragma unroll
      for (int j=0;j<4;++j)
        gload16(src + (size_t)mA*HH + ((base+j)&7)*32 + kbA*8, lsA[dst][j] + wid*1024);
    } else {
      int d = (s1 == 1) ? -(int)HH : (int)HH;
      bool e1 = (s1 == 1) ? (lpA >= 1) : (lpA <= LL-2);
      bool e2 = (s1 == 1) ? (lpA >= 2) : (lpA <= LL-3);
      #pragma unroll
      for (int j=0;j<4;++j){
        int co = ((base+j)&7)*32 + kbA*8;
        const u16* hp = h + (size_t)mA*HH + co;
        uint4 u1 = e1 ? *(const uint4*)(hp + d)   : make_uint4(0,0,0,0);
        uint4 u2 = e2 ? *(const uint4*)(hp + 2*d) : make_uint4(0,0,0,0);
        uint4 pv;
        pv.x = bfadd2(u1.x,u2.x); pv.y = bfadd2(u1.y,u2.y);
        pv.z = bfadd2(u1.z,u2.z); pv.w = bfadd2(u1.w,u2.w);
        *(uint4*)(lsA[dst][j] + wid*1024 + lane*16) = pv;
      }
    }
  };

  stage(0, 0);
  stage(1, 1);
  asm volatile("s_waitcnt vmcnt(4)" ::: "memory");
  __builtin_amdgcn_s_barrier();

  #pragma unroll 1
  for (int G = 0; G < 8; ++G){
    if (G < 6) stage(G+2, (G+2)%3);
    int setc = G % 3;
    #pragma unroll
    for (int j = 0; j < 4; ++j){
      int ks = 4*G + j;
      const unsigned char* bstep = bbase + (size_t)ks*28672;
      bf16x8 aa[4];
      #pragma unroll
      for (int mf=0; mf<4; ++mf)
        aa[mf] = *(const bf16x8*)(lsA[setc][j] + mf*1024 + off0);
      if (PASS == 0){
        bf16x8 bg[4];
        #pragma unroll
        for (int g = 0; g < 4; ++g) bg[g] = *(const bf16x8*)(bstep + (size_t)g*4096);
        __builtin_amdgcn_s_setprio(1);
        #pragma unroll
        for (int g = 0; g < 4; ++g)
          #pragma unroll
          for (int mf=0; mf<4; ++mf) acc[g][mf] = mfma16(aa[mf], bg[g], acc[g][mf]);
        __builtin_amdgcn_s_setprio(0);
      } else {
        bf16x8 bg[3];
        #pragma unroll
        for (int g = 0; g < 3; ++g) bg[g] = *(const bf16x8*)(bstep + (size_t)(4+g)*4096);
        bf16x8 b8;
        if (ks < 8) b8 = *(const bf16x8*)(gbase + (size_t)ks*4096);
        __builtin_amdgcn_s_setprio(1);
        #pragma unroll
        for (int g = 0; g < 3; ++g)
          #pragma unroll
          for (int mf=0; mf<4; ++mf) acc[g][mf] = mfma16(aa[mf], bg[g], acc[g][mf]);
        if (ks < 8){
          #pragma unroll
          for (int mf=0; mf<4; ++mf) acc[3][mf] = mfma16(aa[mf], b8, acc[3][mf]);
        }
        __builtin_amdgcn_s_setprio(0);
      }
    }
    asm volatile("s_waitcnt vmcnt(4)" ::: "memory");
    __builtin_amdgcn_s_barrier();
  }

  int col = nt*64 + wid*16 + li;

  if (PASS == 0){
    // store raw pre-activations of gates 0-3, packed bf16x4 per cell
    #pragma unroll
    for (int mf=0; mf<4; ++mf)
      #pragma unroll
      for (int j=0; j<4; ++j){
        int m = m0 + mf*16 + kg*4 + j;
        ushort4 pv;
        pv.x = f2b(acc[0][mf][j]); pv.y = f2b(acc[1][mf][j]);
        pv.z = f2b(acc[2][mf][j]); pv.w = f2b(acc[3][mf][j]);
        pre4[(size_t)m*HH + col] = pv;
      }
    return;
  }

  // ---- PASS 1 epilogue ----
  float wdv[NG];
  #pragma unroll
  for (int g=0; g<NG; ++g) wdv[g] = wd[(size_t)(g*BB+b)*HH + col];
  float dcv = dc[b*HH + col];
  float gx  = gx2f[b*HH + col];
  float num = 0.f, den = 0.f, msh = 0.f, msc = 0.f;

  #pragma unroll
  for (int mf=0; mf<4; ++mf)
  #pragma unroll
  for (int j=0; j<4; ++j){
    int m = m0 + mf*16 + kg*4 + j;
    int lp = m & (LL-1);
    float fm = (float)mask[m];
    const float* cp = c + (size_t)m*HH + col;
    float cc = cp[0];
    float cbv = 0.f, cav = 0.f;
    if (lp >= 1)    cbv += cp[-(int)HH];
    if (lp >= 2)    cbv += cp[-2*(int)HH];
    if (lp <= LL-2) cav += cp[HH];
    if (lp <= LL-3) cav += cp[2*HH];
    ushort4 pv = pre4[(size_t)m*HH + col];
    float s0 = fsig(b2f(pv.x) + wdv[0]);
    float s1 = fsig(b2f(pv.y) + wdv[1]);
    float s2 = fsig(b2f(pv.z) + wdv[2]);
    float s3 = fsig(b2f(pv.w) + wdv[3]);
    float s4 = fsig(acc[0][mf][j] + wdv[4]);
    float s5 = fsig(acc[1][mf][j] + wdv[5]);
    float u  = ftanh(acc[2][mf][j] + wdv[6]);
    float e0 = __expf(s0), e1 = __expf(s1), e2 = __expf(s2), e3 = __expf(s3), e4 = __expf(s4);
    float inv = __fdividef(1.0f, e0+e1+e2+e3+e4);
    float cn = (e0*cbv + e1*cav + e2*cc + e3*dcv + e4*u)*inv;
    float hn = s5*ftanh(cn);
    float ho = hn*fm, co = cn*fm;
    hout[(size_t)m*HH + col] = f2b(ho);
    if (wc)   cout[(size_t)m*HH + col] = co;
    if (wf32) hf32[(size_t)m*HH + col] = ho;
    float s8 = fsig(acc[3][mf][j] + gx);
    float e8 = fm * __expf(s8);
    num += e8 * cc;
    den += e8;
    msh += ho; msc += co;
  }
  num += __shfl_xor(num, 16); num += __shfl_xor(num, 32);
  den += __shfl_xor(den, 16); den += __shfl_xor(den, 32);
  msh += __shfl_xor(msh, 16); msh += __shfl_xor(msh, 32);
  msc += __shfl_xor(msc, 16); msc += __shfl_xor(msc, 32);
  if (kg == 0){
    size_t tix = (size_t)(m0>>6)*HH + col;
    pnumP[tix] = num;
    pdenP[tix] = den;
    pmh[tix]   = msh;
    pmc[tix]   = msc;
  }
}

// ================= fused single-pass k_main (round-17 fallback) =================
__global__ __launch_bounds__(256, 2) void k_main(const u16* __restrict__ h,
    const float* __restrict__ c, const u16* __restrict__ embp,
    const int* __restrict__ mask,
    const u16* __restrict__ Bp, const u16* __restrict__ Gp,
    const float* __restrict__ wd, const float* __restrict__ dc,
    const float* __restrict__ gx2f,
    u16* __restrict__ hout, float* __restrict__ cout, float* __restrict__ hf32,
    float* __restrict__ pnumP, float* __restrict__ pdenP,
    float* __restrict__ pmh, float* __restrict__ pmc, int wf32, int wc){
  __shared__ __align__(16) unsigned char lsA[3][4][4096];

  int tid = threadIdx.x, lane = tid & 63, wid = tid >> 6;
  int flat = blockIdx.x;
  int xcd = flat & 7, q = flat >> 3;
  int nt  = xcd >> 1;
  int mt  = (xcd & 1)*256 + q;
  int m0 = mt << 6, b = m0 >> 10;
  int li = lane & 15, kg = lane >> 4;

  int kbA = (lane&3) ^ ((lane>>3)&3);
  int mA = m0 + wid*16 + (lane>>2), lpA = mA & (LL-1);
  int off0 = li*64 + ((kg ^ ((li>>1)&3))<<4);

  const unsigned char* bbase = (const unsigned char*)Bp
      + (size_t)nt*32*28672 + (size_t)(wid*16+li)*64 + (size_t)kg*16;
  const unsigned char* gbase = (const unsigned char*)Gp
      + (size_t)nt*8*4096  + (size_t)(wid*16+li)*64 + (size_t)kg*16;

  f32x4 acc[NG][4];
  f32x4 acc8[4];
  #pragma unroll
  for (int g=0; g<NG; ++g)
    #pragma unroll
    for (int mf=0; mf<4; ++mf) acc[g][mf] = (f32x4)0.f;
  #pragma unroll
  for (int mf=0; mf<4; ++mf) acc8[mf] = (f32x4)0.f;

  auto stage = [&](int Gs, int dst){
    int base = 4*Gs, s1 = base >> 3;
    if (s1 == 0 || s1 == 3){
      const u16* src = (s1 == 0) ? h : embp;
      #pragma unroll
      for (int j=0;j<4;++j)
        gload16(src + (size_t)mA*HH + ((base+j)&7)*32 + kbA*8, lsA[dst][j] + wid*1024);
    } else {
      int d = (s1 == 1) ? -(int)HH : (int)HH;
      bool e1 = (s1 == 1) ? (lpA >= 1) : (lpA <= LL-2);
      bool e2 = (s1 == 1) ? (lpA >= 2) : (lpA <= LL-3);
      #pragma unroll
      for (int j=0;j<4;++j){
        int co = ((base+j)&7)*32 + kbA*8;
        const u16* hp = h + (size_t)mA*HH + co;
        uint4 u1 = e1 ? *(const uint4*)(hp + d)   : make_uint4(0,0,0,0);
        uint4 u2 = e2 ? *(const uint4*)(hp + 2*d) : make_uint4(0,0,0,0);
        uint4 pv;
        pv.x = bfadd2(u1.x,u2.x); pv.y = bfadd2(u1.y,u2.y);
        pv.z = bfadd2(u1.z,u2.z); pv.w = bfadd2(u1.w,u2.w);
        *(uint4*)(lsA[dst][j] + wid*1024 + lane*16) = pv;
      }
    }
  };

  stage(0, 0);
  stage(1, 1);
  asm volatile("s_waitcnt vmcnt(4)" ::: "memory");
  __builtin_amdgcn_s_barrier();

  #pragma unroll 1
  for (int G = 0; G < 8; ++G){
    if (G < 6) stage(G+2, (G+2)%3);
    int setc = G % 3;
    #pragma unroll
    for (int j = 0; j < 4; ++j){
      int ks = 4*G + j;
      const unsigned char* bstep = bbase + (size_t)ks*28672;
      bf16x8 bg[NG];
      #pragma unroll
      for (int g = 0; g < NG; ++g) bg[g] = *(const bf16x8*)(bstep + g*4096);
      bf16x8 aa[4];
      #pragma unroll
      for (int mf=0; mf<4; ++mf)
        aa[mf] = *(const bf16x8*)(lsA[setc][j] + mf*1024 + off0);
      __builtin_amdgcn_s_setprio(1);
      #pragma unroll
      for (int g = 0; g < NG; ++g)
        #pragma unroll
        for (int mf=0; mf<4; ++mf) acc[g][mf] = mfma16(aa[mf], bg[g], acc[g][mf]);
      if (ks < 8){
        bf16x8 b8 = *(const bf16x8*)(gbase + (size_t)ks*4096);
        #pragma unroll
        for (int mf=0; mf<4; ++mf) acc8[mf] = mfma16(aa[mf], b8, acc8[mf]);
      }
      __builtin_amdgcn_s_setprio(0);
    }
    asm volatile("s_waitcnt vmcnt(4)" ::: "memory");
    __builtin_amdgcn_s_barrier();
  }

  int col = nt*64 + wid*16 + li;
  float wdv[NG];
  #pragma unroll
  for (int g=0; g<NG; ++g) wdv[g] = wd[(size_t)(g*BB+b)*HH + col];
  float dcv = dc[b*HH + col];
  float gx  = gx2f[b*HH + col];
  float num = 0.f, den = 0.f, msh = 0.f, msc = 0.f;

  #pragma unroll
  for (int mf=0; mf<4; ++mf)
  #pragma unroll
  for (int j=0; j<4; ++j){
    int m = m0 + mf*16 + kg*4 + j;
    int lp = m & (LL-1);
    float fm = (float)mask[m];
    const float* cp = c + (size_t)m*HH + col;
    float cc = cp[0];
    float cbv = 0.f, cav = 0.f;
    if (lp >= 1)    cbv += cp[-(int)HH];
    if (lp >= 2)    cbv += cp[-2*(int)HH];
    if (lp <= LL-2) cav += cp[HH];
    if (lp <= LL-3) cav += cp[2*HH];
    float s0 = fsig(acc[0][mf][j] + wdv[0]);
    float s1 = fsig(acc[1][mf][j] + wdv[1]);
    float s2 = fsig(acc[2][mf][j] + wdv[2]);
    float s3 = fsig(acc[3][mf][j] + wdv[3]);
    float s4 = fsig(acc[4][mf][j] + wdv[4]);
    float s5 = fsig(acc[5][mf][j] + wdv[5]);
    float u  = ftanh(acc[6][mf][j] + wdv[6]);
    float e0 = __expf(s0), e1 = __expf(s1), e2 = __expf(s2), e3 = __expf(s3), e4 = __expf(s4);
    float inv = __fdividef(1.0f, e0+e1+e2+e3+e4);
    float cn = (e0*cbv + e1*cav + e2*cc + e3*dcv + e4*u)*inv;
    float hn = s5*ftanh(cn);
    float ho = hn*fm, co = cn*fm;
    hout[(size_t)m*HH + col] = f2b(ho);
    if (wc)   cout[(size_t)m*HH + col] = co;
    if (wf32) hf32[(size_t)m*HH + col] = ho;
    float s8 = fsig(acc8[mf][j] + gx);
    float e8 = fm * __expf(s8);
    num += e8 * cc;
    den += e8;
    msh += ho; msc += co;
  }
  num += __shfl_xor(num, 16); num += __shfl_xor(num, 32);
  den += __shfl_xor(den, 16); den += __shfl_xor(den, 32);
  msh += __shfl_xor(msh, 16); msh += __shfl_xor(msh, 32);
  msc += __shfl_xor(msc, 16); msc += __shfl_xor(msc, 32);
  if (kg == 0){
    size_t tix = (size_t)(m0>>6)*HH + col;
    pnumP[tix] = num;
    pdenP[tix] = den;
    pmh[tix]   = msh;
    pmc[tix]   = msc;
  }
}

extern "C" void kernel_launch(void* const* d_in, const int* in_sizes, int n_in,
                              void* d_out, int out_size, void* d_ws, size_t ws_size,
                              hipStream_t stream) {
  const float* win   = (const float*)d_in[0];
  const int*   mask  = (const int*)d_in[1];
  // d_in[2] = num_layers (always 3)
  const float* ih    = (const float*)d_in[3];
  const float* ic    = (const float*)d_in[4];
  const float* Wx    = (const float*)d_in[5];
  const float* Wh    = (const float*)d_in[6];
  const float* Wi    = (const float*)d_in[7];
  const float* Wd    = (const float*)d_in[8];
  const float* bias  = (const float*)d_in[9];
  const float* gWx   = (const float*)d_in[10];
  const float* gWh   = (const float*)d_in[11];
  const float* gb    = (const float*)d_in[12];

  const size_t SZ = (size_t)BB*LL*HH;   // 8388608
  char* p = (char*)d_ws;
  auto alloc = [&](size_t bytes)->char*{ char* r = p; p += (bytes + 255) & ~(size_t)255; return r; };
  u16*   hA    = (u16*)  alloc(SZ*2);            // 16MB
  u16*   hB    = (u16*)  alloc(SZ*2);            // 16MB
  float* cA    = (float*)alloc(SZ*4);            // 32MB
  float* cB    = (float*)d_out;                  // d_out doubles as 2nd c buffer
  u16*   embp  = (u16*)  alloc(SZ*2);            // 16MB precomputed emb bf16
  u16*   Bp    = (u16*)  alloc((size_t)1835008*2);
  u16*   Gp    = (u16*)  alloc((size_t)65536*2);
  float* combc = (float*)alloc(BB*HH*4);
  float* dh0   = (float*)alloc(BB*HH*4);
  float* dh1   = (float*)alloc(BB*HH*4);
  float* dc0   = (float*)alloc(BB*HH*4);
  float* dc1   = (float*)alloc(BB*HH*4);
  float* g_d   = (float*)alloc(BB*HH*4);
  float* g_o   = (float*)alloc(BB*HH*4);
  float* gx2f  = (float*)alloc(BB*HH*4);
  float* wd    = (float*)alloc((size_t)NG*BB*HH*4);
  float* pnumP = (float*)alloc((size_t)512*HH*4);
  float* pdenP = (float*)alloc((size_t)512*HH*4);
  float* pmh   = (float*)alloc((size_t)512*HH*4);
  float* pmc   = (float*)alloc((size_t)512*HH*4);
  ushort4* pre4 = (ushort4*)alloc(SZ*8);         // 67MB — two-pass scratch (LAST)
  size_t used = (size_t)(p - (char*)d_ws);
  int two_pass = (used <= ws_size);
  float* dhb[2] = {dh0, dh1};
  float* dcb[2] = {dc0, dc1};

  k_wpack<<<7168, 256, 0, stream>>>(Wx, Wh, Wi, Bp);
  k_gw2pack<<<256, 256, 0, stream>>>(gWh, Gp);
  k_embpack<<<4096, 256, 0, stream>>>(win, mask, embp);
  k_init<<<dim3(BB,16), 256, 0, stream>>>(ih, ic, mask, hA, cA, pmh, pmc);

  u16 *h_cur = hA, *h_nxt = hB;
  float *c_cur = cA, *c_nxt = cB;
  for (int layer = 0; layer < 3; ++layer){
    int l0 = (layer == 0);
    const float* dh_l = l0 ? (const float*)nullptr : dhb[(layer+1)&1];
    const float* dc_l = l0 ? combc : dcb[(layer+1)&1];
    k_ms<<<dim3(BB,8), 256, 0, stream>>>(pmh, pmc, dh_l, gWx, gWh, gb, Wd, bias,
                                         g_d, g_o, gx2f, wd, combc, l0);
    int last = (layer == 2);
    if (two_pass){
      k_mainP<0><<<2048, 256, 0, stream>>>(h_cur, c_cur, embp, mask, Bp, Gp, wd, dc_l, gx2f,
                                           pre4, h_nxt, c_nxt, (float*)d_out, pnumP, pdenP,
                                           pmh, pmc, last, !last);
      k_mainP<1><<<2048, 256, 0, stream>>>(h_cur, c_cur, embp, mask, Bp, Gp, wd, dc_l, gx2f,
                                           pre4, h_nxt, c_nxt, (float*)d_out, pnumP, pdenP,
                                           pmh, pmc, last, !last);
    } else {
      k_main<<<2048, 256, 0, stream>>>(h_cur, c_cur, embp, mask, Bp, Gp, wd, dc_l, gx2f,
                                       h_nxt, c_nxt, (float*)d_out, pnumP, pdenP,
                                       pmh, pmc, last, !last);
    }
    k_dummy2<<<BB, 256, 0, stream>>>(pnumP, pdenP, g_d, g_o, dc_l, dhb[layer&1], dcb[layer&1]);
    u16* th = h_cur; h_cur = h_nxt; h_nxt = th;
    float* tc = c_cur; c_cur = c_nxt; c_nxt = tc;
  }
}

// Round 19
// 657.892 us; speedup vs baseline: 1.1689x; 1.1689x over previous
//
#include <hip/hip_runtime.h>
#include <hip/hip_bf16.h>
#include <math.h>

#define BB 32
#define LL 1024
#define DD 256
#define HH 256
#define NG 7
#define HW (HH*HH)       /* 65536 */
#define WhS (2*HH*HH)    /* Wh per-gate stride */

typedef short bf16x8 __attribute__((ext_vector_type(8)));
typedef float f32x4  __attribute__((ext_vector_type(4)));
typedef unsigned short u16;
typedef unsigned int u32;

__device__ __forceinline__ float sigm(float x){ return 1.0f/(1.0f + expf(-x)); }
__device__ __forceinline__ float fsig(float x){ return __fdividef(1.0f, 1.0f + __expf(-x)); }
__device__ __forceinline__ float ftanh(float x){ return 1.0f - __fdividef(2.0f, 1.0f + __expf(2.0f*x)); }
__device__ __forceinline__ u16 f2b(float f){
  u32 u = __float_as_uint(f);
  return (u16)((u + 0x7fffu + ((u>>16)&1u)) >> 16);   // RNE
}
__device__ __forceinline__ float b2f(u16 b){ return __uint_as_float(((u32)b)<<16); }
__device__ __forceinline__ float4 ld4(const float* p){ return *reinterpret_cast<const float4*>(p); }
__device__ __forceinline__ u32 packf2(float lo, float hi){
  float2 s; s.x = lo; s.y = hi;
  __hip_bfloat162 r = __float22bfloat162_rn(s);
  return *reinterpret_cast<u32*>(&r);
}
// sum of two bf16 pairs (packed dwords), RNE back to packed bf16
__device__ __forceinline__ u32 bfadd2(u32 a, u32 b){
  float lo = __uint_as_float(a << 16)        + __uint_as_float(b << 16);
  float hi = __uint_as_float(a & 0xffff0000u) + __uint_as_float(b & 0xffff0000u);
  return packf2(lo, hi);
}

__device__ __forceinline__ void gload16(const void* g, void* l){
  __builtin_amdgcn_global_load_lds(
    (const __attribute__((address_space(1))) unsigned int*)g,
    (__attribute__((address_space(3))) unsigned int*)l, 16, 0, 0);
}
__device__ __forceinline__ f32x4 mfma16(bf16x8 a, bf16x8 b, f32x4 c){
  return __builtin_amdgcn_mfma_f32_16x16x32_bf16(a, b, c, 0, 0, 0);
}

// ---------------- init: h,c + layer-0 mean partials ----------------
__global__ __launch_bounds__(256) void k_init(const float* __restrict__ ih, const float* __restrict__ ic,
    const int* __restrict__ mask, u16* __restrict__ h, float* __restrict__ c,
    float* __restrict__ pmh, float* __restrict__ pmc){
  int b = blockIdx.x, ch = blockIdx.y, k = threadIdx.x;
  size_t base = ((size_t)b*LL + ch*64)*HH + k;
  float sh = 0.f, sc = 0.f;
  for (int l = 0; l < 64; ++l){
    size_t idx = base + (size_t)l*HH;
    float fm = (float)mask[b*LL + ch*64 + l];
    float hv = (ih[idx]*0.1f - 0.05f)*fm;
    float cv = (ic[idx]*0.1f - 0.05f)*fm;
    h[idx] = f2b(hv);
    c[idx] = cv;
    sh += hv; sc += cv;
  }
  pmh[(size_t)(b*16+ch)*HH + k] = sh;
  pmc[(size_t)(b*16+ch)*HH + k] = sc;
}

// ---------------- emb precompute (once per call): embp = bf16(win*mask) ----------------
__global__ __launch_bounds__(256) void k_embpack(const float* __restrict__ win,
    const int* __restrict__ mask, u16* __restrict__ embp){
  int idx = blockIdx.x*256 + threadIdx.x;     // 0..1048575 (8 elems each)
  int m = idx >> 5, c8 = (idx & 31) << 3;
  float fm = (float)mask[m];
  float4 w0 = ld4(win + (size_t)m*DD + c8);
  float4 w1 = ld4(win + (size_t)m*DD + c8 + 4);
  uint4 pv;
  pv.x = packf2(w0.x*fm, w0.y*fm); pv.y = packf2(w0.z*fm, w0.w*fm);
  pv.z = packf2(w1.x*fm, w1.y*fm); pv.w = packf2(w1.z*fm, w1.w*fm);
  *(uint4*)(embp + (size_t)m*HH + c8) = pv;
}

// ---------------- fused mean + small GEMMs, grid (BB, 8) ----------------
// comb = mean_l h reconstructed from pmh partials (written by k_init / k_main epi)
__global__ __launch_bounds__(256) void k_ms(const float* __restrict__ pmh, const float* __restrict__ pmc,
    const float* __restrict__ dh_in,
    const float* __restrict__ gWx, const float* __restrict__ gWh, const float* __restrict__ gb,
    const float* __restrict__ Wd, const float* __restrict__ bias,
    float* __restrict__ g_d, float* __restrict__ g_o, float* __restrict__ gx2f, float* __restrict__ wd,
    float* __restrict__ combc_out, int l0flag){
  __shared__ float dsh[HH], csh[HH];
  int b = blockIdx.x, g = blockIdx.y, k = threadIdx.x;
  float sh = 0.f;
  for (int ch = 0; ch < 16; ++ch) sh += pmh[(size_t)(b*16+ch)*HH + k];
  float comb = sh*(1.0f/LL);
  csh[k] = comb;
  dsh[k] = l0flag ? comb : dh_in[b*HH+k];
  __syncthreads();
  if (g < NG){
    float aw = bias[g*HH+k];
    const float* W = Wd + (size_t)g*HW + k;
    for (int j = 0; j < HH; ++j) aw += dsh[j]*W[(size_t)j*HH];
    wd[(size_t)(g*BB + b)*HH + k] = aw;
  } else {
    float ad = gb[0*HH+k], ao = gb[1*HH+k], ax = gb[2*HH+k];
    for (int j = 0; j < HH; ++j){
      float dv = dsh[j], cv = csh[j];
      ad += dv*gWx[j*HH+k]      + cv*gWh[j*HH+k];
      ao += dv*gWx[HW + j*HH+k] + cv*gWh[HW + j*HH+k];
      ax += dv*gWx[2*HW + j*HH+k];
    }
    g_d[b*HH+k] = sigm(ad);
    g_o[b*HH+k] = sigm(ao);
    gx2f[b*HH+k] = ax;
    if (l0flag){
      float sc = 0.f;
      for (int ch = 0; ch < 16; ++ch) sc += pmc[(size_t)(b*16+ch)*HH + k];
      combc_out[b*HH+k] = sc*(1.0f/LL);
    }
  }
}

// ---------------- weight pack: frag-contiguous (B read direct from L2) ----------------
__global__ __launch_bounds__(256) void k_wpack(const float* __restrict__ Wx, const float* __restrict__ Wh,
    const float* __restrict__ Wi, u16* __restrict__ Bp){
  int idx = blockIdx.x*256 + threadIdx.x;      // 0..1835007
  int img = idx / 14336, e = idx % 14336;
  int nt = img >> 5, ks = img & 31;
  int g = e >> 11, r = e & 2047;
  int n = r >> 5, kblk = (r>>3)&3, j = r&7;
  int K = ks*32 + kblk*8 + j;
  int N = nt*64 + n;
  int slice = K >> 8, kr = K & 255;
  float v;
  if (slice == 0)      v = Wx[(size_t)g*HW  + (size_t)kr*HH + N];
  else if (slice == 1) v = Wh[(size_t)g*WhS + (size_t)kr*HH + N];
  else if (slice == 2) v = Wh[(size_t)g*WhS + (size_t)(256+kr)*HH + N];
  else                 v = Wi[(size_t)g*HW  + (size_t)kr*HH + N];
  Bp[idx] = f2b(v);
}

__global__ __launch_bounds__(256) void k_gw2pack(const float* __restrict__ gWh, u16* __restrict__ Gp){
  int idx = blockIdx.x*256 + threadIdx.x;      // 0..65535
  int img = idx >> 11, r = idx & 2047;         // img = nt*8+ks
  int nt = img >> 3, ks = img & 7;
  int n = r >> 5, kblk = (r>>3)&3, j = r&7;
  int K = ks*32 + kblk*8 + j, N = nt*64 + n;
  Gp[idx] = f2b(gWh[2*HW + (size_t)K*HH + N]);
}

__global__ __launch_bounds__(256) void k_dummy2(const float* __restrict__ pnumP, const float* __restrict__ pdenP,
    const float* __restrict__ g_d, const float* __restrict__ g_o, const float* __restrict__ dc,
    float* __restrict__ dh_n, float* __restrict__ dc_n){
  int b = blockIdx.x, k = threadIdx.x;
  float num = 0.f, den = 0.f;
  for (int mt = 0; mt < 16; ++mt){
    num += pnumP[(size_t)(b*16+mt)*HH + k];
    den += pdenP[(size_t)(b*16+mt)*HH + k];
  }
  float ed = expf(g_d[b*HH+k]);
  float v = (num + ed*dc[b*HH+k])/(den + ed);
  dc_n[b*HH+k] = v;
  dh_n[b*HH+k] = g_o[b*HH+k]*tanhf(v);
}

// ---------------- main fused MFMA GEMM (7 gates + g_f) + epilogue ----------------
// K-steps grouped 4-per-barrier, 3-deep LDS A-pipeline, counted vmcnt(4).
// B loads software-pipelined as half-step ping-pong (H1(ks) before H0-MFMAs,
// H0(ks+1) before H1-MFMAs). Best measured configuration (round 17: 205.8 µs).
__global__ __launch_bounds__(256, 2) void k_main(const u16* __restrict__ h,
    const float* __restrict__ c, const u16* __restrict__ embp,
    const int* __restrict__ mask,
    const u16* __restrict__ Bp, const u16* __restrict__ Gp,
    const float* __restrict__ wd, const float* __restrict__ dc,
    const float* __restrict__ gx2f,
    u16* __restrict__ hout, float* __restrict__ cout, float* __restrict__ hf32,
    float* __restrict__ pnumP, float* __restrict__ pdenP,
    float* __restrict__ pmh, float* __restrict__ pmc, int wf32, int wc){
  __shared__ __align__(16) unsigned char lsA[3][4][4096];   // 48 KB: 3 sets x 4 steps

  int tid = threadIdx.x, lane = tid & 63, wid = tid >> 6;
  int flat = blockIdx.x;
  int xcd = flat & 7, q = flat >> 3;           // HW round-robins blockIdx over XCDs
  int nt  = xcd >> 1;                          // XCD pair owns one nt (Bp slice L2-resident)
  int mt  = (xcd & 1)*256 + q;                 // bijective: 2048 = 8*256
  int m0 = mt << 6, b = m0 >> 10;
  int li = lane & 15, kg = lane >> 4;

  // A write-side geometry (proven conflict-free layout)
  int kbA = (lane&3) ^ ((lane>>3)&3);
  int mA = m0 + wid*16 + (lane>>2), lpA = mA & (LL-1);

  // A read-side swizzled offset (mf-invariant part)
  int off0 = li*64 + ((kg ^ ((li>>1)&3))<<4);

  // B frag global bases (bytes)
  const unsigned char* bbase = (const unsigned char*)Bp
      + (size_t)nt*32*28672 + (size_t)(wid*16+li)*64 + (size_t)kg*16;
  const unsigned char* gbase = (const unsigned char*)Gp
      + (size_t)nt*8*4096  + (size_t)(wid*16+li)*64 + (size_t)kg*16;

  f32x4 acc[NG][4];
  f32x4 acc8[4];
  #pragma unroll
  for (int g=0; g<NG; ++g)
    #pragma unroll
    for (int mf=0; mf<4; ++mf) acc[g][mf] = (f32x4)0.f;
  #pragma unroll
  for (int mf=0; mf<4; ++mf) acc8[mf] = (f32x4)0.f;

  // stage group Gs (steps 4Gs..4Gs+3) into set dst; slice = Gs>>1 uniform within group
  auto stage = [&](int Gs, int dst){
    int base = 4*Gs, s1 = base >> 3;
    if (s1 == 0 || s1 == 3){                   // h or emb: pure global_load_lds
      const u16* src = (s1 == 0) ? h : embp;
      #pragma unroll
      for (int j=0;j<4;++j)
        gload16(src + (size_t)mA*HH + ((base+j)&7)*32 + kbA*8, lsA[dst][j] + wid*1024);
    } else {                                    // hb / ha: reg bf16 shift-add + ds_write
      int d = (s1 == 1) ? -(int)HH : (int)HH;
      bool e1 = (s1 == 1) ? (lpA >= 1) : (lpA <= LL-2);
      bool e2 = (s1 == 1) ? (lpA >= 2) : (lpA <= LL-3);
      #pragma unroll
      for (int j=0;j<4;++j){
        int co = ((base+j)&7)*32 + kbA*8;
        const u16* hp = h + (size_t)mA*HH + co;
        uint4 u1 = e1 ? *(const uint4*)(hp + d)   : make_uint4(0,0,0,0);
        uint4 u2 = e2 ? *(const uint4*)(hp + 2*d) : make_uint4(0,0,0,0);
        uint4 pv;
        pv.x = bfadd2(u1.x,u2.x); pv.y = bfadd2(u1.y,u2.y);
        pv.z = bfadd2(u1.z,u2.z); pv.w = bfadd2(u1.w,u2.w);
        *(uint4*)(lsA[dst][j] + wid*1024 + lane*16) = pv;
      }
    }
  };

  // ---- prologue: stage groups 0 and 1 (both slice 0: pure gload) ----
  stage(0, 0);
  stage(1, 1);
  asm volatile("s_waitcnt vmcnt(4)" ::: "memory");   // set0 complete (oldest 4 drained)
  __builtin_amdgcn_s_barrier();

  // software-pipeline preloads: A frags of step (0,0), B half0 (gates 0-3) of ks=0
  bf16x8 aa[4];
  #pragma unroll
  for (int mf=0; mf<4; ++mf)
    aa[mf] = *(const bf16x8*)(lsA[0][0] + mf*1024 + off0);
  bf16x8 b0[4];
  #pragma unroll
  for (int g=0; g<4; ++g) b0[g] = *(const bf16x8*)(bbase + (size_t)g*4096);

  #pragma unroll 1
  for (int G = 0; G < 8; ++G){
    if (G < 6) stage(G+2, (G+2)%3);          // 2-group-ahead prefetch
    int setc = G % 3;
    #pragma unroll
    for (int j = 0; j < 4; ++j){
      int ks = 4*G + j;
      const unsigned char* bstep = bbase + (size_t)ks*28672;
      // issue B half1 (gates 4-6, + g_f) — in flight during H0 MFMAs
      bf16x8 b1[3];
      #pragma unroll
      for (int g=0; g<3; ++g) b1[g] = *(const bf16x8*)(bstep + (size_t)(4+g)*4096);
      bf16x8 b8;
      if (ks < 8) b8 = *(const bf16x8*)(gbase + (size_t)ks*4096);
      // MFMA half0 (consumes preloaded b0)
      __builtin_amdgcn_s_setprio(1);
      #pragma unroll
      for (int g=0; g<4; ++g)
        #pragma unroll
        for (int mf=0; mf<4; ++mf) acc[g][mf] = mfma16(aa[mf], b0[g], acc[g][mf]);
      __builtin_amdgcn_s_setprio(0);
      // issue next step's B half0 — in flight during H1 MFMAs (crosses barrier at j=3)
      if (ks < 31){
        const unsigned char* bnext = bbase + (size_t)(ks+1)*28672;
        #pragma unroll
        for (int g=0; g<4; ++g) b0[g] = *(const bf16x8*)(bnext + (size_t)g*4096);
      }
      // MFMA half1
      __builtin_amdgcn_s_setprio(1);
      #pragma unroll
      for (int g=0; g<3; ++g)
        #pragma unroll
        for (int mf=0; mf<4; ++mf) acc[4+g][mf] = mfma16(aa[mf], b1[g], acc[4+g][mf]);
      if (ks < 8){
        #pragma unroll
        for (int mf=0; mf<4; ++mf) acc8[mf] = mfma16(aa[mf], b8, acc8[mf]);
      }
      __builtin_amdgcn_s_setprio(0);
      // next step's A frags (within group; cross-group read happens after barrier)
      if (j < 3){
        #pragma unroll
        for (int mf=0; mf<4; ++mf)
          aa[mf] = *(const bf16x8*)(lsA[setc][j+1] + mf*1024 + off0);
      }
    }
    // counted wait: newest 4 in flight = next-step b0 prefetch (exempted)
    asm volatile("s_waitcnt vmcnt(4)" ::: "memory");
    __builtin_amdgcn_s_barrier();
    if (G < 7){
      int setn = (G+1) % 3;
      #pragma unroll
      for (int mf=0; mf<4; ++mf)
        aa[mf] = *(const bf16x8*)(lsA[setn][0] + mf*1024 + off0);
    }
  }

  // ---- epilogue ----
  int col = nt*64 + wid*16 + li;
  float wdv[NG];
  #pragma unroll
  for (int g=0; g<NG; ++g) wdv[g] = wd[(size_t)(g*BB+b)*HH + col];
  float dcv = dc[b*HH + col];
  float gx  = gx2f[b*HH + col];
  float num = 0.f, den = 0.f, msh = 0.f, msc = 0.f;

  #pragma unroll
  for (int mf=0; mf<4; ++mf)
  #pragma unroll
  for (int j=0; j<4; ++j){
    int m = m0 + mf*16 + kg*4 + j;
    int lp = m & (LL-1);
    float fm = (float)mask[m];
    const float* cp = c + (size_t)m*HH + col;
    float cc = cp[0];
    float cbv = 0.f, cav = 0.f;
    if (lp >= 1)    cbv += cp[-(int)HH];
    if (lp >= 2)    cbv += cp[-2*(int)HH];
    if (lp <= LL-2) cav += cp[HH];
    if (lp <= LL-3) cav += cp[2*HH];
    float s0 = fsig(acc[0][mf][j] + wdv[0]);
    float s1 = fsig(acc[1][mf][j] + wdv[1]);
    float s2 = fsig(acc[2][mf][j] + wdv[2]);
    float s3 = fsig(acc[3][mf][j] + wdv[3]);
    float s4 = fsig(acc[4][mf][j] + wdv[4]);
    float s5 = fsig(acc[5][mf][j] + wdv[5]);
    float u  = ftanh(acc[6][mf][j] + wdv[6]);
    // 5-way softmax without max-subtraction: inputs in (0,1), exp safe
    float e0 = __expf(s0), e1 = __expf(s1), e2 = __expf(s2), e3 = __expf(s3), e4 = __expf(s4);
    float inv = __fdividef(1.0f, e0+e1+e2+e3+e4);
    float cn = (e0*cbv + e1*cav + e2*cc + e3*dcv + e4*u)*inv;
    float hn = s5*ftanh(cn);
    float ho = hn*fm, co = cn*fm;
    hout[(size_t)m*HH + col] = f2b(ho);
    if (wc)   cout[(size_t)m*HH + col] = co;
    if (wf32) hf32[(size_t)m*HH + col] = ho;
    float s8 = fsig(acc8[mf][j] + gx);
    float e8 = fm * __expf(s8);
    num += e8 * cc;
    den += e8;
    msh += ho; msc += co;       // next-layer mean partials
  }
  num += __shfl_xor(num, 16); num += __shfl_xor(num, 32);
  den += __shfl_xor(den, 16); den += __shfl_xor(den, 32);
  msh += __shfl_xor(msh, 16); msh += __shfl_xor(msh, 32);
  msc += __shfl_xor(msc, 16); msc += __shfl_xor(msc, 32);
  if (kg == 0){
    size_t tix = (size_t)(m0>>6)*HH + col;
    pnumP[tix] = num;
    pdenP[tix] = den;
    pmh[tix]   = msh;
    pmc[tix]   = msc;
  }
}

extern "C" void kernel_launch(void* const* d_in, const int* in_sizes, int n_in,
                              void* d_out, int out_size, void* d_ws, size_t ws_size,
                              hipStream_t stream) {
  const float* win   = (const float*)d_in[0];
  const int*   mask  = (const int*)d_in[1];
  // d_in[2] = num_layers (always 3)
  const float* ih    = (const float*)d_in[3];
  const float* ic    = (const float*)d_in[4];
  const float* Wx    = (const float*)d_in[5];
  const float* Wh    = (const float*)d_in[6];
  const float* Wi    = (const float*)d_in[7];
  const float* Wd    = (const float*)d_in[8];
  const float* bias  = (const float*)d_in[9];
  const float* gWx   = (const float*)d_in[10];
  const float* gWh   = (const float*)d_in[11];
  const float* gb    = (const float*)d_in[12];

  const size_t SZ = (size_t)BB*LL*HH;   // 8388608
  char* p = (char*)d_ws;
  auto alloc = [&](size_t bytes)->char*{ char* r = p; p += (bytes + 255) & ~(size_t)255; return r; };
  u16*   hA    = (u16*)  alloc(SZ*2);            // 16MB
  u16*   hB    = (u16*)  alloc(SZ*2);            // 16MB
  float* cA    = (float*)alloc(SZ*4);            // 32MB
  float* cB    = (float*)d_out;                  // d_out doubles as 2nd c buffer
  u16*   embp  = (u16*)  alloc(SZ*2);            // 16MB precomputed emb bf16
  u16*   Bp    = (u16*)  alloc((size_t)1835008*2);
  u16*   Gp    = (u16*)  alloc((size_t)65536*2);
  float* combc = (float*)alloc(BB*HH*4);
  float* dh0   = (float*)alloc(BB*HH*4);
  float* dh1   = (float*)alloc(BB*HH*4);
  float* dc0   = (float*)alloc(BB*HH*4);
  float* dc1   = (float*)alloc(BB*HH*4);
  float* g_d   = (float*)alloc(BB*HH*4);
  float* g_o   = (float*)alloc(BB*HH*4);
  float* gx2f  = (float*)alloc(BB*HH*4);
  float* wd    = (float*)alloc((size_t)NG*BB*HH*4);
  float* pnumP = (float*)alloc((size_t)512*HH*4);
  float* pdenP = (float*)alloc((size_t)512*HH*4);
  float* pmh   = (float*)alloc((size_t)512*HH*4);
  float* pmc   = (float*)alloc((size_t)512*HH*4);
  float* dhb[2] = {dh0, dh1};
  float* dcb[2] = {dc0, dc1};

  k_wpack<<<7168, 256, 0, stream>>>(Wx, Wh, Wi, Bp);
  k_gw2pack<<<256, 256, 0, stream>>>(gWh, Gp);
  k_embpack<<<4096, 256, 0, stream>>>(win, mask, embp);
  k_init<<<dim3(BB,16), 256, 0, stream>>>(ih, ic, mask, hA, cA, pmh, pmc);

  u16 *h_cur = hA, *h_nxt = hB;
  float *c_cur = cA, *c_nxt = cB;
  for (int layer = 0; layer < 3; ++layer){
    int l0 = (layer == 0);
    const float* dh_l = l0 ? (const float*)nullptr : dhb[(layer+1)&1];
    const float* dc_l = l0 ? combc : dcb[(layer+1)&1];
    // fused mean(from partials) + small GEMMs; for layer 0 also emits combc (= dc_l)
    k_ms<<<dim3(BB,8), 256, 0, stream>>>(pmh, pmc, dh_l, gWx, gWh, gb, Wd, bias,
                                         g_d, g_o, gx2f, wd, combc, l0);
    int last = (layer == 2);
    k_main<<<2048, 256, 0, stream>>>(h_cur, c_cur, embp, mask, Bp, Gp, wd, dc_l, gx2f,
                                     h_nxt, c_nxt, (float*)d_out, pnumP, pdenP,
                                     pmh, pmc, last, !last);
    k_dummy2<<<BB, 256, 0, stream>>>(pnumP, pdenP, g_d, g_o, dc_l, dhb[layer&1], dcb[layer&1]);
    u16* th = h_cur; h_cur = h_nxt; h_nxt = th;
    float* tc = c_cur; c_cur = c_nxt; c_nxt = tc;
  }
}